// Round 2
// baseline (161.385 us; speedup 1.0000x reference)
//
#include <hip/hip_runtime.h>
#include <hip/hip_cooperative_groups.h>

namespace cg = cooperative_groups;

#define NB 4
#define NP 8
#define NV 2048
#define NE 2048
#define NF 4096
#define BIGV 1.0e10f
#define NCOMBO (NB * NP)       // 32
#define NSPAN 16               // edge spans (128 edges each)
#define NVC 16                 // vertex chunks per combo
#define VC 128                 // vertices per chamfer block
#define NBLK (NCOMBO * NVC)    // 512 blocks: exactly 2 per CU
#define XPAD 65                // eds_xy row stride (float4): +1 -> span bases 4 banks apart
#define EPAD 132               // e2a row stride (floats): +4 pad, keeps 16B alignment
#define PPAD 132               // part row stride (floats)

// ws: spart[512], cpart[512], volpart[512]

__device__ __forceinline__ void finalize_out(
    const float* __restrict__ spart, const float* __restrict__ cpart,
    const float* __restrict__ volpart, const float* __restrict__ tv,
    float* __restrict__ out, const int tid)
{
    __shared__ float pc[NCOMBO];
    __shared__ float rv[4];
    // per-combo masked mean from 16 vchunk partials (vectorized: 4x float4 each)
    if (tid < NCOMBO) {
        const float4* s4 = (const float4*)(spart + (tid << 4));
        const float4* c4 = (const float4*)(cpart + (tid << 4));
        float S = 0.0f, C = 0.0f;
        #pragma unroll
        for (int j = 0; j < 4; j++) {
            const float4 a = s4[j], d = c4[j];
            S += (a.x + a.y) + (a.z + a.w);
            C += (d.x + d.y) + (d.z + d.w);
        }
        pc[tid] = S / fmaxf(C, 1.0f);
    }
    // volume: wave w reduces the 128 block-partials of batch b=w
    const int w = tid >> 6, lane = tid & 63;
    float vs = volpart[(w << 7) + lane] + volpart[(w << 7) + 64 + lane];
    #pragma unroll
    for (int off = 32; off > 0; off >>= 1) vs += __shfl_down(vs, off);
    if (lane == 0) rv[w] = vs;
    __syncthreads();
    if (tid < NB) {
        float a = 0.0f;
        #pragma unroll
        for (int q = 0; q < NP; q++) a += pc[tid * NP + q];
        out[tid] = a * (1.0f / NP);
        const float d = fabsf(rv[tid]) - tv[tid];
        out[4 + tid] = d * d;
    }
}

// One block = one (combo, vchunk): min over ALL 2048 edges for 128 vertices
// (16 edge-spans x 16 vertex-groups of 8) + 32 volume faces. COOP=1: grid.sync
// then block 0 finalizes (single dispatch). COOP=0: partials only (fallback).
template <int COOP>
__global__ __launch_bounds__(256) void fused_all(
    const float* __restrict__ xs, const float* __restrict__ pm,
    const float* __restrict__ edgemaps, const int* __restrict__ elen,
    const int* __restrict__ faces, const void* __restrict__ maskp,
    const float* __restrict__ tv,
    float* __restrict__ spart, float* __restrict__ cpart,
    float* __restrict__ volpart, float* __restrict__ out)
{
    __shared__ __align__(16) float4 eds_xy[NSPAN * XPAD];  // 16.3 KB: packed edge xy pairs
    __shared__ __align__(16) float  e2a[NSPAN * EPAD];     // 8.25 KB: |e|^2 (BIG if invalid)
    __shared__ __align__(16) float  part[NSPAN * PPAD];    // 8.25 KB: per-span vertex mins
    __shared__ float reds[2], redc[2];
    const int tid = threadIdx.x;
    const int bid = blockIdx.x;
    const int combo  = bid >> 4;   // b*8 + p
    const int vchunk = bid & 15;
    const int b = combo >> 3;
    const int p = combo & 7;

    // ---- stage all 2048 edges SoA-packed: 4 coalesced float4 (=8 edges) per thread ----
    const int len = elen[combo];
    const float4* emapf4 = (const float4*)(edgemaps + (size_t)combo * NE * 2);
    #pragma unroll
    for (int j = 0; j < 4; j++) {
        const int t = tid + (j << 8);          // edge-pair index 0..1023
        float4 f4 = emapf4[t];                 // edges 2t, 2t+1
        const int e0 = t << 1;
        float a2, b2;
        if (e0 < len)     { a2 = f4.x * f4.x + f4.y * f4.y; }
        else              { f4.x = 0.0f; f4.y = 0.0f; a2 = BIGV; }
        if (e0 + 1 < len) { b2 = f4.z * f4.z + f4.w * f4.w; }
        else              { f4.z = 0.0f; f4.w = 0.0f; b2 = BIGV; }
        const int sp = t >> 6, pr = t & 63;
        eds_xy[sp * XPAD + pr] = f4;
        e2a[sp * EPAD + (pr << 1) + 0] = a2;
        e2a[sp * EPAD + (pr << 1) + 1] = b2;
    }

    // ---- project 8 owned vertices (coalesced dwordx4 loads of 24 contiguous floats) ----
    const float* M = pm + p * 12;              // uniform -> scalar loads
    const float m00 = M[0], m01 = M[1], m02 = M[2],  m03 = M[3];
    const float m10 = M[4], m11 = M[5], m12 = M[6],  m13 = M[7];
    const float m20 = M[8], m21 = M[9], m22 = M[10], m23 = M[11];

    const int vgroup = tid & 15;
    const int span   = tid >> 4;
    const int v0     = vchunk * VC + (vgroup << 3);

    float c24[24];
    {
        const float4* xv = (const float4*)(xs + ((size_t)b * NV + v0) * 3);
        #pragma unroll
        for (int j = 0; j < 6; j++) ((float4*)c24)[j] = xv[j];
    }
    float px2[8], py2[8], v2[8], mn[8];
    #pragma unroll
    for (int i = 0; i < 8; i++) {
        const float x = c24[3 * i], y = c24[3 * i + 1], z = c24[3 * i + 2];
        const float r0 = m00 * x + m01 * y + m02 * z + m03;
        const float r1 = m10 * x + m11 * y + m12 * z + m13;
        const float r2 = m20 * x + m21 * y + m22 * z + m23;
        const float inv = 1.0f / r2;           // r2 ~ 2.0 by construction
        const float px = r0 * inv;
        const float py = r1 * inv;
        px2[i] = -2.0f * px;
        py2[i] = -2.0f * py;
        v2[i]  = px * px + py * py;            // folded out of the min, added back at end
        mn[i]  = 3.0e38f;
    }

    // ---- volume gathers issued early (wave 0 lanes 0..31); waits land post-hot-loop ----
    float fvol = 0.0f;
    if (tid < 32) {
        const int f = (bid << 5) + tid;        // global face 0..16383, contiguous per b
        const int* fc = faces + (size_t)f * 3;
        const int i0 = fc[0], i1 = fc[1], i2 = fc[2];
        const float* xb = xs + (size_t)(f >> 12) * NV * 3;
        const float ax = xb[i0 * 3], ay = xb[i0 * 3 + 1], az = xb[i0 * 3 + 2];
        const float bx = xb[i1 * 3], by = xb[i1 * 3 + 1], bz = xb[i1 * 3 + 2];
        const float cx = xb[i2 * 3], cy = xb[i2 * 3 + 1], cz = xb[i2 * 3 + 2];
        const float crx = ay * bz - az * by;
        const float cry = az * bx - ax * bz;
        const float crz = ax * by - ay * bx;
        fvol = (crx * cx + cry * cy + crz * cz) * (1.0f / 6.0f);
    }
    __syncthreads();

    // ---- hot loop: 128 edges x 8 verts; 3 b128 per 4 edges, min3-fusable chain ----
    const float4* xp = eds_xy + span * XPAD;
    const float*  ep = e2a + span * EPAD;
    #pragma unroll 2
    for (int k = 0; k < 32; k++) {
        const float4 xy01 = xp[2 * k];
        const float4 xy23 = xp[2 * k + 1];
        const float4 ee   = *(const float4*)(ep + 4 * k);
        #pragma unroll
        for (int i = 0; i < 8; i++) {
            const float d0 = fmaf(py2[i], xy01.y, fmaf(px2[i], xy01.x, ee.x));
            const float d1 = fmaf(py2[i], xy01.w, fmaf(px2[i], xy01.z, ee.y));
            const float d2 = fmaf(py2[i], xy23.y, fmaf(px2[i], xy23.x, ee.z));
            const float d3 = fmaf(py2[i], xy23.w, fmaf(px2[i], xy23.z, ee.w));
            mn[i] = fminf(fminf(mn[i], d0), d1);   // -> v_min3_f32 if backend folds
            mn[i] = fminf(fminf(mn[i], d2), d3);
        }
    }

    // ---- per-span partial mins -> LDS; cross-span min + masked partial sum ----
    #pragma unroll
    for (int i = 0; i < 8; i++)
        part[span * PPAD + (vgroup << 3) + i] = mn[i] + v2[i];

    // boundary_mask dtype sniff (uniform): int32 0/1 words <=1; packed bytes exceed 1
    const unsigned* mw = (const unsigned*)maskp;
    bool as_int = true;
    #pragma unroll
    for (int k = 0; k < 16; k++)
        if (mw[k] > 1u) as_int = false;

    __syncthreads();
    float s = 0.0f, c = 0.0f;
    if (tid < VC) {
        float m = part[tid];
        #pragma unroll
        for (int sp = 1; sp < NSPAN; sp++)
            m = fminf(m, part[sp * PPAD + tid]);
        const size_t mix = (size_t)combo * NV + vchunk * VC + tid;
        const float msk = as_int ? (((const int*)maskp)[mix] ? 1.0f : 0.0f)
                                 : (((const unsigned char*)maskp)[mix] ? 1.0f : 0.0f);
        s = m * msk;
        c = msk;
    }
    #pragma unroll
    for (int off = 32; off > 0; off >>= 1) {
        s += __shfl_down(s, off);
        c += __shfl_down(c, off);
    }
    if (tid < VC && (tid & 63) == 0) { reds[tid >> 6] = s; redc[tid >> 6] = c; }

    // volume wave-reduce (lanes 32..63 contribute 0; all lanes active here)
    #pragma unroll
    for (int off = 32; off > 0; off >>= 1) fvol += __shfl_down(fvol, off);

    __syncthreads();
    if (tid == 0) {
        spart[bid]   = reds[0] + reds[1];
        cpart[bid]   = redc[0] + redc[1];
        volpart[bid] = fvol;
    }

    if (COOP) {
        __threadfence();
        cg::this_grid().sync();
        if (bid == 0) finalize_out(spart, cpart, volpart, tv, out, tid);
    }
}

// Fallback finalize (only used if cooperative launch is rejected).
__global__ __launch_bounds__(256) void finalize_k(
    const float* __restrict__ spart, const float* __restrict__ cpart,
    const float* __restrict__ volpart, const float* __restrict__ tv,
    float* __restrict__ out)
{
    finalize_out(spart, cpart, volpart, tv, out, threadIdx.x);
}

extern "C" void kernel_launch(void* const* d_in, const int* in_sizes, int n_in,
                              void* d_out, int out_size, void* d_ws, size_t ws_size,
                              hipStream_t stream)
{
    const float* xs       = (const float*)d_in[0];
    const float* pm       = (const float*)d_in[1];
    const float* edgemaps = (const float*)d_in[2];
    const int*   elen     = (const int*)d_in[3];
    const void*  mask     = d_in[4];
    const int*   faces    = (const int*)d_in[5];
    const float* tv       = (const float*)d_in[6];
    float* out = (float*)d_out;

    float* spart   = (float*)d_ws;              // 512 floats
    float* cpart   = spart + NBLK;              // 512 floats
    float* volpart = cpart + NBLK;              // 512 floats

    void* args[] = { (void*)&xs, (void*)&pm, (void*)&edgemaps, (void*)&elen,
                     (void*)&faces, (void*)&mask, (void*)&tv,
                     (void*)&spart, (void*)&cpart, (void*)&volpart, (void*)&out };
    hipError_t err = hipLaunchCooperativeKernel(fused_all<1>, dim3(NBLK), dim3(256),
                                                args, 0, stream);
    if (err != hipSuccess) {
        // graph-capture or co-residency rejection: plain 2-dispatch path
        fused_all<0><<<dim3(NBLK), dim3(256), 0, stream>>>(
            xs, pm, edgemaps, elen, faces, mask, tv, spart, cpart, volpart, out);
        finalize_k<<<dim3(1), dim3(256), 0, stream>>>(spart, cpart, volpart, tv, out);
    }
}

// Round 3
// 78.791 us; speedup vs baseline: 2.0483x; 2.0483x over previous
//
#include <hip/hip_runtime.h>

#define NB 4
#define NP 8
#define NV 2048
#define NE 2048
#define NF 4096
#define BIGV 1.0e10f
#define NCOMBO (NB * NP)       // 32
#define NSPAN 16               // edge spans (128 edges each)
#define NVC 16                 // vertex chunks per combo
#define VC 128                 // vertices per chamfer block
#define NBLK (NCOMBO * NVC)    // 512 blocks: exactly 2 per CU
#define XPAD 65                // eds_xy row stride (float4): +1 -> span bases 4 banks apart
#define EPAD 132               // e2a row stride (floats): +4 pad, keeps 16B alignment
#define PPAD 132               // part row stride (floats)

// ws: spart[512], cpart[512], volpart[512]
//
// NOTE (round-2 post-mortem): cg::this_grid().sync() with 512 blocks cost ~65us
// on MI355X (device-scope barrier atomics serialized across 8 non-coherent
// XCDs; VALUBusy was 12% of a 77us dispatch). A second 1-block dispatch is
// ~4us. Plain 2-dispatch is the right structure on this chip.

// K1: one block = one (combo, vchunk): min over ALL 2048 edges for 128
// vertices (16 edge-spans x 16 vertex-groups of 8) + 32 volume faces per
// block. Emits per-block masked-sum/count/volume partials only.
__global__ __launch_bounds__(256) void fused_all(
    const float* __restrict__ xs, const float* __restrict__ pm,
    const float* __restrict__ edgemaps, const int* __restrict__ elen,
    const int* __restrict__ faces, const void* __restrict__ maskp,
    float* __restrict__ spart, float* __restrict__ cpart,
    float* __restrict__ volpart)
{
    __shared__ __align__(16) float4 eds_xy[NSPAN * XPAD];  // 16.3 KB: packed edge xy pairs
    __shared__ __align__(16) float  e2a[NSPAN * EPAD];     // 8.25 KB: |e|^2 (BIG if invalid)
    __shared__ __align__(16) float  part[NSPAN * PPAD];    // 8.25 KB: per-span vertex mins
    __shared__ float reds[2], redc[2];
    const int tid = threadIdx.x;
    const int bid = blockIdx.x;
    const int combo  = bid >> 4;   // b*8 + p
    const int vchunk = bid & 15;
    const int b = combo >> 3;
    const int p = combo & 7;

    // ---- stage all 2048 edges SoA-packed: 4 coalesced float4 (=8 edges) per thread ----
    const int len = elen[combo];
    const float4* emapf4 = (const float4*)(edgemaps + (size_t)combo * NE * 2);
    #pragma unroll
    for (int j = 0; j < 4; j++) {
        const int t = tid + (j << 8);          // edge-pair index 0..1023
        float4 f4 = emapf4[t];                 // edges 2t, 2t+1
        const int e0 = t << 1;
        float a2, b2;
        if (e0 < len)     { a2 = f4.x * f4.x + f4.y * f4.y; }
        else              { f4.x = 0.0f; f4.y = 0.0f; a2 = BIGV; }
        if (e0 + 1 < len) { b2 = f4.z * f4.z + f4.w * f4.w; }
        else              { f4.z = 0.0f; f4.w = 0.0f; b2 = BIGV; }
        const int sp = t >> 6, pr = t & 63;
        eds_xy[sp * XPAD + pr] = f4;
        e2a[sp * EPAD + (pr << 1) + 0] = a2;
        e2a[sp * EPAD + (pr << 1) + 1] = b2;
    }

    // ---- project 8 owned vertices (coalesced dwordx4 loads of 24 contiguous floats) ----
    const float* M = pm + p * 12;              // uniform -> scalar loads
    const float m00 = M[0], m01 = M[1], m02 = M[2],  m03 = M[3];
    const float m10 = M[4], m11 = M[5], m12 = M[6],  m13 = M[7];
    const float m20 = M[8], m21 = M[9], m22 = M[10], m23 = M[11];

    const int vgroup = tid & 15;
    const int span   = tid >> 4;
    const int v0     = vchunk * VC + (vgroup << 3);

    float c24[24];
    {
        const float4* xv = (const float4*)(xs + ((size_t)b * NV + v0) * 3);
        #pragma unroll
        for (int j = 0; j < 6; j++) ((float4*)c24)[j] = xv[j];
    }
    float px2[8], py2[8], v2[8], mn[8];
    #pragma unroll
    for (int i = 0; i < 8; i++) {
        const float x = c24[3 * i], y = c24[3 * i + 1], z = c24[3 * i + 2];
        const float r0 = m00 * x + m01 * y + m02 * z + m03;
        const float r1 = m10 * x + m11 * y + m12 * z + m13;
        const float r2 = m20 * x + m21 * y + m22 * z + m23;
        const float inv = 1.0f / r2;           // r2 ~ 2.0 by construction
        const float px = r0 * inv;
        const float py = r1 * inv;
        px2[i] = -2.0f * px;
        py2[i] = -2.0f * py;
        v2[i]  = px * px + py * py;            // folded out of the min, added back at end
        mn[i]  = 3.0e38f;
    }

    // ---- volume gathers issued early (wave 0 lanes 0..31); drain at the barrier ----
    float fvol = 0.0f;
    if (tid < 32) {
        const int f = (bid << 5) + tid;        // global face 0..16383, contiguous per b
        const int* fc = faces + (size_t)f * 3;
        const int i0 = fc[0], i1 = fc[1], i2 = fc[2];
        const float* xb = xs + (size_t)(f >> 12) * NV * 3;
        const float ax = xb[i0 * 3], ay = xb[i0 * 3 + 1], az = xb[i0 * 3 + 2];
        const float bx = xb[i1 * 3], by = xb[i1 * 3 + 1], bz = xb[i1 * 3 + 2];
        const float cx = xb[i2 * 3], cy = xb[i2 * 3 + 1], cz = xb[i2 * 3 + 2];
        const float crx = ay * bz - az * by;
        const float cry = az * bx - ax * bz;
        const float crz = ax * by - ay * bx;
        fvol = (crx * cx + cry * cy + crz * cz) * (1.0f / 6.0f);
    }
    __syncthreads();

    // ---- hot loop: 128 edges x 8 verts; 3 b128 per 4 edges, min3-fusable chain ----
    const float4* xp = eds_xy + span * XPAD;
    const float*  ep = e2a + span * EPAD;
    #pragma unroll 2
    for (int k = 0; k < 32; k++) {
        const float4 xy01 = xp[2 * k];
        const float4 xy23 = xp[2 * k + 1];
        const float4 ee   = *(const float4*)(ep + 4 * k);
        #pragma unroll
        for (int i = 0; i < 8; i++) {
            const float d0 = fmaf(py2[i], xy01.y, fmaf(px2[i], xy01.x, ee.x));
            const float d1 = fmaf(py2[i], xy01.w, fmaf(px2[i], xy01.z, ee.y));
            const float d2 = fmaf(py2[i], xy23.y, fmaf(px2[i], xy23.x, ee.z));
            const float d3 = fmaf(py2[i], xy23.w, fmaf(px2[i], xy23.z, ee.w));
            mn[i] = fminf(fminf(mn[i], d0), d1);   // -> v_min3_f32 if backend folds
            mn[i] = fminf(fminf(mn[i], d2), d3);
        }
    }

    // ---- per-span partial mins -> LDS; cross-span min + masked partial sum ----
    #pragma unroll
    for (int i = 0; i < 8; i++)
        part[span * PPAD + (vgroup << 3) + i] = mn[i] + v2[i];

    // boundary_mask dtype sniff (uniform): int32 0/1 words <=1; packed bytes exceed 1
    const unsigned* mw = (const unsigned*)maskp;
    bool as_int = true;
    #pragma unroll
    for (int k = 0; k < 16; k++)
        if (mw[k] > 1u) as_int = false;

    __syncthreads();
    float s = 0.0f, c = 0.0f;
    if (tid < VC) {
        float m = part[tid];
        #pragma unroll
        for (int sp = 1; sp < NSPAN; sp++)
            m = fminf(m, part[sp * PPAD + tid]);
        const size_t mix = (size_t)combo * NV + vchunk * VC + tid;
        const float msk = as_int ? (((const int*)maskp)[mix] ? 1.0f : 0.0f)
                                 : (((const unsigned char*)maskp)[mix] ? 1.0f : 0.0f);
        s = m * msk;
        c = msk;
    }
    #pragma unroll
    for (int off = 32; off > 0; off >>= 1) {
        s += __shfl_down(s, off);
        c += __shfl_down(c, off);
    }
    if (tid < VC && (tid & 63) == 0) { reds[tid >> 6] = s; redc[tid >> 6] = c; }

    // volume wave-reduce (lanes 32..63 contribute 0; all lanes active here)
    #pragma unroll
    for (int off = 32; off > 0; off >>= 1) fvol += __shfl_down(fvol, off);

    __syncthreads();
    if (tid == 0) {
        spart[bid]   = reds[0] + reds[1];
        cpart[bid]   = redc[0] + redc[1];
        volpart[bid] = fvol;
    }
}

// K2: finalize both outputs (1 small block).
__global__ __launch_bounds__(256) void finalize_k(
    const float* __restrict__ spart, const float* __restrict__ cpart,
    const float* __restrict__ volpart, const float* __restrict__ tv,
    float* __restrict__ out)
{
    __shared__ float pc[NCOMBO];
    __shared__ float rv[4];
    const int tid = threadIdx.x;
    // per-combo masked mean from 16 vchunk partials (vectorized: 4x float4 each)
    if (tid < NCOMBO) {
        const float4* s4 = (const float4*)(spart + (tid << 4));
        const float4* c4 = (const float4*)(cpart + (tid << 4));
        float S = 0.0f, C = 0.0f;
        #pragma unroll
        for (int j = 0; j < 4; j++) {
            const float4 a = s4[j], d = c4[j];
            S += (a.x + a.y) + (a.z + a.w);
            C += (d.x + d.y) + (d.z + d.w);
        }
        pc[tid] = S / fmaxf(C, 1.0f);
    }
    // volume: wave w reduces the 128 block-partials of batch b=w
    const int w = tid >> 6, lane = tid & 63;
    float vs = volpart[(w << 7) + lane] + volpart[(w << 7) + 64 + lane];
    #pragma unroll
    for (int off = 32; off > 0; off >>= 1) vs += __shfl_down(vs, off);
    if (lane == 0) rv[w] = vs;
    __syncthreads();
    if (tid < NB) {
        float a = 0.0f;
        #pragma unroll
        for (int q = 0; q < NP; q++) a += pc[tid * NP + q];
        out[tid] = a * (1.0f / NP);
        const float d = fabsf(rv[tid]) - tv[tid];
        out[4 + tid] = d * d;
    }
}

extern "C" void kernel_launch(void* const* d_in, const int* in_sizes, int n_in,
                              void* d_out, int out_size, void* d_ws, size_t ws_size,
                              hipStream_t stream)
{
    const float* xs       = (const float*)d_in[0];
    const float* pm       = (const float*)d_in[1];
    const float* edgemaps = (const float*)d_in[2];
    const int*   elen     = (const int*)d_in[3];
    const void*  mask     = d_in[4];
    const int*   faces    = (const int*)d_in[5];
    const float* tv       = (const float*)d_in[6];
    float* out = (float*)d_out;

    float* spart   = (float*)d_ws;              // 512 floats
    float* cpart   = spart + NBLK;              // 512 floats
    float* volpart = cpart + NBLK;              // 512 floats

    fused_all<<<dim3(NBLK), dim3(256), 0, stream>>>(
        xs, pm, edgemaps, elen, faces, mask, spart, cpart, volpart);
    finalize_k<<<dim3(1), dim3(256), 0, stream>>>(spart, cpart, volpart, tv, out);
}

// Round 4
// 77.237 us; speedup vs baseline: 2.0895x; 1.0201x over previous
//
#include <hip/hip_runtime.h>

#define NB 4
#define NP 8
#define NV 2048
#define NE 2048
#define NF 4096
#define BIGV 1.0e10f
#define NCOMBO (NB * NP)       // 32
#define NSPAN 16               // edge spans (128 edges each)
#define NVC 16                 // vertex chunks per combo
#define VC 128                 // vertices per chamfer block
#define NBLK (NCOMBO * NVC)    // 512 blocks: exactly 2 per CU
#define SSTRIDE 132            // span row stride (floats): 128 + 4 -> span bases 4 banks apart
#define PPAD 132               // part row stride (floats)

// ws: spart[512], cpart[512], volpart[512]
//
// NOTE (round-2 post-mortem): cg::this_grid().sync() with 512 blocks cost ~65us
// on MI355X (device-scope barrier across 8 non-coherent XCDs). A 1-block second
// dispatch is ~3us. Plain 2-dispatch is the right structure on this chip.
//
// NOTE (round-4): hot loop uses v_pk_fma_f32 (2 f32 FMA/instr, CDNA3+) +
// min3-foldable min chain: 3 instr / 2 edge-distances vs 6 scalar. LDS is SoA
// (ex[], ey[], e2[]) so each ds_read_b128 feeds packed pairs directly.

typedef float f32x2 __attribute__((ext_vector_type(2)));

__device__ __forceinline__ f32x2 pk_fma(f32x2 a, f32x2 b, f32x2 c) {
    f32x2 d;
    asm("v_pk_fma_f32 %0, %1, %2, %3" : "=v"(d) : "v"(a), "v"(b), "v"(c));
    return d;
}

// K1: one block = one (combo, vchunk): min over ALL 2048 edges for 128
// vertices (16 edge-spans x 16 vertex-groups of 8) + 32 volume faces per
// block. Emits per-block masked-sum/count/volume partials only.
__global__ __launch_bounds__(256) void fused_all(
    const float* __restrict__ xs, const float* __restrict__ pm,
    const float* __restrict__ edgemaps, const int* __restrict__ elen,
    const int* __restrict__ faces, const void* __restrict__ maskp,
    float* __restrict__ spart, float* __restrict__ cpart,
    float* __restrict__ volpart)
{
    __shared__ __align__(16) float s_ex[NSPAN * SSTRIDE];  // 8.25 KB
    __shared__ __align__(16) float s_ey[NSPAN * SSTRIDE];  // 8.25 KB
    __shared__ __align__(16) float s_e2[NSPAN * SSTRIDE];  // 8.25 KB (BIG if invalid)
    __shared__ __align__(16) float part[NSPAN * PPAD];     // 8.25 KB per-span vertex mins
    __shared__ float reds[2], redc[2];
    const int tid = threadIdx.x;
    const int bid = blockIdx.x;
    const int combo  = bid >> 4;   // b*8 + p
    const int vchunk = bid & 15;
    const int b = combo >> 3;
    const int p = combo & 7;

    // ---- stage all 2048 edges SoA: thread handles 2 edge-quads (8 edges) ----
    const int len = elen[combo];
    const float4* emapf4 = (const float4*)(edgemaps + (size_t)combo * NE * 2);
    #pragma unroll
    for (int j = 0; j < 2; j++) {
        const int q = tid + (j << 8);          // edge quad 0..511 (edges 4q..4q+3)
        const float4 f0 = emapf4[2 * q];       // ex0,ey0,ex1,ey1 (32B/lane contiguous)
        const float4 f1 = emapf4[2 * q + 1];   // ex2,ey2,ex3,ey3
        float ex[4] = { f0.x, f0.z, f1.x, f1.z };
        float ey[4] = { f0.y, f0.w, f1.y, f1.w };
        float e2[4];
        const int e0 = q << 2;
        #pragma unroll
        for (int k = 0; k < 4; k++) {
            if (e0 + k < len) {
                e2[k] = ex[k] * ex[k] + ey[k] * ey[k];
            } else {
                ex[k] = 0.0f; ey[k] = 0.0f; e2[k] = BIGV;  // ref: d2 -> BIG for invalid e
            }
        }
        const int sp = q >> 5, pr = (q & 31) << 2;   // 32 quads per 128-edge span
        *(float4*)&s_ex[sp * SSTRIDE + pr] = make_float4(ex[0], ex[1], ex[2], ex[3]);
        *(float4*)&s_ey[sp * SSTRIDE + pr] = make_float4(ey[0], ey[1], ey[2], ey[3]);
        *(float4*)&s_e2[sp * SSTRIDE + pr] = make_float4(e2[0], e2[1], e2[2], e2[3]);
    }

    // ---- project 8 owned vertices (coalesced dwordx4 loads of 24 contiguous floats) ----
    const float* M = pm + p * 12;              // uniform -> scalar loads
    const float m00 = M[0], m01 = M[1], m02 = M[2],  m03 = M[3];
    const float m10 = M[4], m11 = M[5], m12 = M[6],  m13 = M[7];
    const float m20 = M[8], m21 = M[9], m22 = M[10], m23 = M[11];

    const int vgroup = tid & 15;
    const int span   = tid >> 4;
    const int v0     = vchunk * VC + (vgroup << 3);

    float c24[24];
    {
        const float4* xv = (const float4*)(xs + ((size_t)b * NV + v0) * 3);
        #pragma unroll
        for (int j = 0; j < 6; j++) ((float4*)c24)[j] = xv[j];
    }
    f32x2 px2[8], py2[8];
    float v2[8], mn[8];
    #pragma unroll
    for (int i = 0; i < 8; i++) {
        const float x = c24[3 * i], y = c24[3 * i + 1], z = c24[3 * i + 2];
        const float r0 = m00 * x + m01 * y + m02 * z + m03;
        const float r1 = m10 * x + m11 * y + m12 * z + m13;
        const float r2 = m20 * x + m21 * y + m22 * z + m23;
        const float inv = 1.0f / r2;           // r2 ~ 2.0 by construction
        const float px = r0 * inv;
        const float py = r1 * inv;
        const float ax = -2.0f * px, ay = -2.0f * py;
        px2[i].x = ax; px2[i].y = ax;          // duplicated pair for pk_fma
        py2[i].x = ay; py2[i].y = ay;
        v2[i]  = px * px + py * py;            // folded out of the min, added back at end
        mn[i]  = 3.0e38f;
    }

    // ---- volume gathers issued early (wave 0 lanes 0..31); drain at the barrier ----
    float fvol = 0.0f;
    if (tid < 32) {
        const int f = (bid << 5) + tid;        // global face 0..16383, contiguous per b
        const int* fc = faces + (size_t)f * 3;
        const int i0 = fc[0], i1 = fc[1], i2 = fc[2];
        const float* xb = xs + (size_t)(f >> 12) * NV * 3;
        const float ax = xb[i0 * 3], ay = xb[i0 * 3 + 1], az = xb[i0 * 3 + 2];
        const float bx = xb[i1 * 3], by = xb[i1 * 3 + 1], bz = xb[i1 * 3 + 2];
        const float cx = xb[i2 * 3], cy = xb[i2 * 3 + 1], cz = xb[i2 * 3 + 2];
        const float crx = ay * bz - az * by;
        const float cry = az * bx - ax * bz;
        const float crz = ax * by - ay * bx;
        fvol = (crx * cx + cry * cy + crz * cz) * (1.0f / 6.0f);
    }
    __syncthreads();

    // ---- hot loop: 4 edges/iter x 8 verts; 3 b128 + 32 pk_fma + 16 min3 per iter ----
    const float* bx = s_ex + span * SSTRIDE;
    const float* by = s_ey + span * SSTRIDE;
    const float* b2 = s_e2 + span * SSTRIDE;
    #pragma unroll 2
    for (int k = 0; k < 32; k++) {
        const float4 ex4 = *(const float4*)(bx + 4 * k);
        const float4 ey4 = *(const float4*)(by + 4 * k);
        const float4 e24 = *(const float4*)(b2 + 4 * k);
        f32x2 exA, exB, eyA, eyB, e2A, e2B;
        exA.x = ex4.x; exA.y = ex4.y;  exB.x = ex4.z; exB.y = ex4.w;
        eyA.x = ey4.x; eyA.y = ey4.y;  eyB.x = ey4.z; eyB.y = ey4.w;
        e2A.x = e24.x; e2A.y = e24.y;  e2B.x = e24.z; e2B.y = e24.w;
        #pragma unroll
        for (int i = 0; i < 8; i++) {
            const f32x2 dA = pk_fma(py2[i], eyA, pk_fma(px2[i], exA, e2A));
            const f32x2 dB = pk_fma(py2[i], eyB, pk_fma(px2[i], exB, e2B));
            mn[i] = fminf(fminf(mn[i], dA.x), dA.y);   // -> v_min3_f32
            mn[i] = fminf(fminf(mn[i], dB.x), dB.y);
        }
    }

    // ---- per-span partial mins -> LDS; cross-span min + masked partial sum ----
    #pragma unroll
    for (int i = 0; i < 8; i++)
        part[span * PPAD + (vgroup << 3) + i] = mn[i] + v2[i];

    // boundary_mask dtype sniff (uniform): int32 0/1 words <=1; packed bytes exceed 1
    const unsigned* mw = (const unsigned*)maskp;
    bool as_int = true;
    #pragma unroll
    for (int k = 0; k < 16; k++)
        if (mw[k] > 1u) as_int = false;

    __syncthreads();
    float s = 0.0f, c = 0.0f;
    if (tid < VC) {
        float m = part[tid];
        #pragma unroll
        for (int sp = 1; sp < NSPAN; sp++)
            m = fminf(m, part[sp * PPAD + tid]);
        const size_t mix = (size_t)combo * NV + vchunk * VC + tid;
        const float msk = as_int ? (((const int*)maskp)[mix] ? 1.0f : 0.0f)
                                 : (((const unsigned char*)maskp)[mix] ? 1.0f : 0.0f);
        s = m * msk;
        c = msk;
    }
    #pragma unroll
    for (int off = 32; off > 0; off >>= 1) {
        s += __shfl_down(s, off);
        c += __shfl_down(c, off);
    }
    if (tid < VC && (tid & 63) == 0) { reds[tid >> 6] = s; redc[tid >> 6] = c; }

    // volume wave-reduce (lanes 32..63 contribute 0; all lanes active here)
    #pragma unroll
    for (int off = 32; off > 0; off >>= 1) fvol += __shfl_down(fvol, off);

    __syncthreads();
    if (tid == 0) {
        spart[bid]   = reds[0] + reds[1];
        cpart[bid]   = redc[0] + redc[1];
        volpart[bid] = fvol;
    }
}

// K2: finalize both outputs (1 small block).
__global__ __launch_bounds__(256) void finalize_k(
    const float* __restrict__ spart, const float* __restrict__ cpart,
    const float* __restrict__ volpart, const float* __restrict__ tv,
    float* __restrict__ out)
{
    __shared__ float pc[NCOMBO];
    __shared__ float rv[4];
    const int tid = threadIdx.x;
    // per-combo masked mean from 16 vchunk partials (vectorized: 4x float4 each)
    if (tid < NCOMBO) {
        const float4* s4 = (const float4*)(spart + (tid << 4));
        const float4* c4 = (const float4*)(cpart + (tid << 4));
        float S = 0.0f, C = 0.0f;
        #pragma unroll
        for (int j = 0; j < 4; j++) {
            const float4 a = s4[j], d = c4[j];
            S += (a.x + a.y) + (a.z + a.w);
            C += (d.x + d.y) + (d.z + d.w);
        }
        pc[tid] = S / fmaxf(C, 1.0f);
    }
    // volume: wave w reduces the 128 block-partials of batch b=w
    const int w = tid >> 6, lane = tid & 63;
    float vs = volpart[(w << 7) + lane] + volpart[(w << 7) + 64 + lane];
    #pragma unroll
    for (int off = 32; off > 0; off >>= 1) vs += __shfl_down(vs, off);
    if (lane == 0) rv[w] = vs;
    __syncthreads();
    if (tid < NB) {
        float a = 0.0f;
        #pragma unroll
        for (int q = 0; q < NP; q++) a += pc[tid * NP + q];
        out[tid] = a * (1.0f / NP);
        const float d = fabsf(rv[tid]) - tv[tid];
        out[4 + tid] = d * d;
    }
}

extern "C" void kernel_launch(void* const* d_in, const int* in_sizes, int n_in,
                              void* d_out, int out_size, void* d_ws, size_t ws_size,
                              hipStream_t stream)
{
    const float* xs       = (const float*)d_in[0];
    const float* pm       = (const float*)d_in[1];
    const float* edgemaps = (const float*)d_in[2];
    const int*   elen     = (const int*)d_in[3];
    const void*  mask     = d_in[4];
    const int*   faces    = (const int*)d_in[5];
    const float* tv       = (const float*)d_in[6];
    float* out = (float*)d_out;

    float* spart   = (float*)d_ws;              // 512 floats
    float* cpart   = spart + NBLK;              // 512 floats
    float* volpart = cpart + NBLK;              // 512 floats

    fused_all<<<dim3(NBLK), dim3(256), 0, stream>>>(
        xs, pm, edgemaps, elen, faces, mask, spart, cpart, volpart);
    finalize_k<<<dim3(1), dim3(256), 0, stream>>>(spart, cpart, volpart, tv, out);
}